// Round 25
// baseline (4476.562 us; speedup 1.0000x reference)
//
#include <hip/hip_runtime.h>
#include <math.h>

// Problem constants (fixed by the reference)
#define NV 20000
#define NH 512
#define NT 1024
#define NB 32
#define MAXD 64

// LSTM persistent-kernel geometry (R13-proven chassis)
#define NGRP 8      // groups (independent batch-row sets); sync domain = 1 group
#define BPG 32      // blocks per group
#define BPB 4       // batch rows per group  (NB / NGRP)
#define UPB 16      // hidden units per block (NH / BPG)
#define NJ 64       // gate rows per block = 4*UPB
#define KTOT 1024   // 2*NH
#define NTH 512
#define KHALF 16    // k floats per thread per half (x + h = 32 floats = 16 pairs)
#define PPADN 576   // padded packed row: 512 pairs + 1 per 8

typedef int v4i __attribute__((ext_vector_type(4)));
typedef __fp16 v2h __attribute__((ext_vector_type(2)));

// R25 pad: +1 u32 per 8 -> chunk base = 9*ks; 9 odd => invertible mod 32 =>
// at fixed kk, the 32 k-slices hit 32 DISTINCT banks (2 lanes/bank per
// wave64 = free, m136). R24's +4-per-32 pad gave 8 lanes/bank (2.94x cost,
// SQ_LDS_BANK_CONFLICT = 1.36e8). Chunks of 8 pairs stay consecutive.
__device__ __forceinline__ int fpadp(int p) { return p + (p >> 3); }

// ws layout: [ path: NV*NH f32 | hbuf: 2*NB*NH f32 | prog: 256 ints ] ~= 41.1 MB

__global__ void init_kernel(float* __restrict__ hbuf, int* __restrict__ prog) {
  int i = blockIdx.x * blockDim.x + threadIdx.x;
  if (i < 2 * NB * NH)
    __hip_atomic_store(&hbuf[i], 0.f, __ATOMIC_RELAXED, __HIP_MEMORY_SCOPE_SYSTEM);
  if (i < 256)
    __hip_atomic_store(&prog[i], 0, __ATOMIC_RELAXED, __HIP_MEMORY_SCOPE_SYSTEM);
}

// One block per node: all 256 threads walk the same parent chain (uniform),
// each thread accumulates 2 of the 512 embedding columns (coalesced).
__global__ __launch_bounds__(256)
void path_kernel(const int* __restrict__ parents,
                 const float* __restrict__ weight,
                 const float* __restrict__ emb,
                 float* __restrict__ path) {
  int v = blockIdx.x;
  int h = threadIdx.x;
  float acc0 = 0.f, acc1 = 0.f;
  float w = 1.f;
  int cur = v;
#pragma unroll 1
  for (int d = 0; d < MAXD; ++d) {
    if (cur < 0) break;
    const float* row = emb + (size_t)cur * NH;
    acc0 = fmaf(w, row[h], acc0);
    acc1 = fmaf(w, row[h + 256], acc1);
    w *= weight[cur];
    cur = parents[cur];
  }
  path[(size_t)v * NH + h] = acc0;
  path[(size_t)v * NH + h + 256] = acc1;
}

// Persistent LSTM, R25 = R24 (packed-f16 fdot2 GEMM, 4.37ms) with the LDS
// bank-conflict fix (stride-9 pad). R24 confirmed the hidden-register-traffic
// theory: FETCH 2.35e7 -> 5.2e5 KB (45x) once w fit in VGPRs (72 used);
// dur 12.4 -> 4.37ms. Remaining visible cost: SQ_LDS_BANK_CONFLICT 1.36e8
// from the packed layout's 8-lanes/bank reads -- fixed here. Staging uses
// scalar u32 stores (chunks no longer 16B-aligned); conflict-free on the
// h-stage (stride 9), minor aliasing on the 2-store x-prefetch.
__global__ __launch_bounds__(NTH, 1)
void lstm_kernel(const int* __restrict__ ev,
                 const float* __restrict__ path,
                 const float* __restrict__ gate_w,
                 const float* __restrict__ gate_b,
                 float* __restrict__ hbuf,   // [2][NB][NH]
                 int* __restrict__ prog,     // [NGRP][BPG] per-producer step ctr
                 float* __restrict__ out) {  // [3][NT][NB][NH]
  __shared__ unsigned int in2[BPB][PPADN];   // packed [x(t) | h(t)] half2
  __shared__ float p_s[32][NJ * BPB + 1];    // stride 257 -> conflict-free
  __shared__ float zred[NJ * BPB];
  __shared__ float c_s[BPB][UPB];

  const int bid = blockIdx.x;
  const int grp = bid >> 5;   // group = consecutive 32-block range
  const int blk = bid & 31;
  const int b0 = grp * BPB;
  const int u0 = blk * UPB;
  const int tid = threadIdx.x;
  const int jg = tid >> 5;   // 0..15: which 4-row group of gate rows
  const int ks = tid & 31;   // 0..31: which k-slice (16 x-floats + 16 h-floats)

  // gate_w slice, packed: w2[jj][0..7] = x-half pairs, [8..15] = h-half pairs
  v2h w2[4][2 * (KHALF / 2)];
#pragma unroll
  for (int jj = 0; jj < 4; ++jj) {
    int r = jg * 4 + jj;                        // 0..63: gate*16 + uu
    int j = (r >> 4) * NH + u0 + (r & 15);      // global gate row
    const float* wx = gate_w + (size_t)j * KTOT + ks * KHALF;
    const float* wh = gate_w + (size_t)j * KTOT + NH + ks * KHALF;
#pragma unroll
    for (int kk = 0; kk < KHALF / 2; ++kk) {
      w2[jj][kk] = __builtin_amdgcn_cvt_pkrtz(wx[2 * kk], wx[2 * kk + 1]);
      w2[jj][8 + kk] = __builtin_amdgcn_cvt_pkrtz(wh[2 * kk], wh[2 * kk + 1]);
    }
  }

  if (tid < BPB * UPB) c_s[tid >> 4][tid & 15] = 0.f;

  // staging maps
  const int sb2 = tid >> 7;          // x-prefetch: row 0..3
  const int off4 = (tid & 127) * 4;  // x-prefetch: 4-float chunk
  const int hrow = tid >> 5;         // h-stage (tid<128): row 0..3
  const int hc16 = (tid & 31) * 16;  // h-stage: 16-float (64B) chunk
  const size_t plane = (size_t)NT * NB * NH;
  int* myprog = prog + grp * BPG + blk;
  const int* pollp4 = prog + grp * BPG + (tid & 7) * 4;

  // pre-stage x(0): load f32, pack to half2 pairs (2 scalar u32 stores)
  {
    int e = ev[0 * NB + b0 + sb2];
    float4 v0 = *(const float4*)(path + (size_t)e * NH + off4);
    int p0 = (tid & 127) * 2;
    unsigned int* d = &in2[sb2][fpadp(p0)];   // p0,p0+1 share an 8-block
    d[0] = __builtin_bit_cast(unsigned int, __builtin_amdgcn_cvt_pkrtz(v0.x, v0.y));
    d[1] = __builtin_bit_cast(unsigned int, __builtin_amdgcn_cvt_pkrtz(v0.z, v0.w));
  }

#pragma unroll 1
  for (int t = 0; t < NT; ++t) {
    const bool more = (t + 1 < NT);

    // ---- wait for group's h(t) producers: 8 lanes x dwordx4 ----
    if (t > 0 && tid < 8) {
      v4i pv;
      for (;;) {
        asm volatile("global_load_dwordx4 %0, %1, off sc0 sc1\n\ts_waitcnt vmcnt(0)"
                     : "=v"(pv) : "v"(pollp4) : "memory");
        bool ok = (pv[0] >= t) && (pv[1] >= t) && (pv[2] >= t) && (pv[3] >= t);
        if ((__ballot(ok) & 0xFFull) == 0xFFull) break;
        __builtin_amdgcn_s_sleep(1);
      }
    }
    __syncthreads();   // A0: poll passed; prev step's LDS reads all complete

    // ---- stage h(t): 128 lanes x one 64B line (4 fused dwordx4) + pack ----
    if (tid < 128) {
      // pair base 256 + (tid&31)*8: one 8-block; banks stride-9 conflict-free
      unsigned int* d = &in2[hrow][fpadp(NH / 2 + (tid & 31) * 8)];
      if (t > 0) {
        const float* hsrc =
            hbuf + ((size_t)(t & 1) * NB + (b0 + hrow)) * NH + hc16;
        float4 ha, hb, hc, hd;
        asm volatile(
            "global_load_dwordx4 %0, %4, off sc0 sc1\n\t"
            "global_load_dwordx4 %1, %4, off offset:16 sc0 sc1\n\t"
            "global_load_dwordx4 %2, %4, off offset:32 sc0 sc1\n\t"
            "global_load_dwordx4 %3, %4, off offset:48 sc0 sc1\n\t"
            "s_waitcnt vmcnt(0)"
            : "=&v"(ha), "=&v"(hb), "=&v"(hc), "=&v"(hd)
            : "v"(hsrc)
            : "memory");
        d[0] = __builtin_bit_cast(unsigned int, __builtin_amdgcn_cvt_pkrtz(ha.x, ha.y));
        d[1] = __builtin_bit_cast(unsigned int, __builtin_amdgcn_cvt_pkrtz(ha.z, ha.w));
        d[2] = __builtin_bit_cast(unsigned int, __builtin_amdgcn_cvt_pkrtz(hb.x, hb.y));
        d[3] = __builtin_bit_cast(unsigned int, __builtin_amdgcn_cvt_pkrtz(hb.z, hb.w));
        d[4] = __builtin_bit_cast(unsigned int, __builtin_amdgcn_cvt_pkrtz(hc.x, hc.y));
        d[5] = __builtin_bit_cast(unsigned int, __builtin_amdgcn_cvt_pkrtz(hc.z, hc.w));
        d[6] = __builtin_bit_cast(unsigned int, __builtin_amdgcn_cvt_pkrtz(hd.x, hd.y));
        d[7] = __builtin_bit_cast(unsigned int, __builtin_amdgcn_cvt_pkrtz(hd.z, hd.w));
      } else {
#pragma unroll
        for (int q = 0; q < 8; ++q) d[q] = 0u;
      }
    }
    __syncthreads();   // A1: h(t) staged

    // ---- GEMM via fdot2: 4 rows x 4 batch x 16 pairs per thread ----
    float acc[4][BPB];
#pragma unroll
    for (int jj = 0; jj < 4; ++jj)
#pragma unroll
      for (int bi = 0; bi < BPB; ++bi) acc[jj][bi] = 0.f;
    {
      const int fbx = fpadp(ks * (KHALF / 2));            // = 9*ks
      const int fbh = fpadp(NH / 2 + ks * (KHALF / 2));   // = 288 + 9*ks
#pragma unroll
      for (int bi = 0; bi < BPB; ++bi) {
        const unsigned int* px = &in2[bi][fbx];
        const unsigned int* ph = &in2[bi][fbh];
#pragma unroll
        for (int kk = 0; kk < KHALF / 2; ++kk) {
          v2h x = __builtin_bit_cast(v2h, px[kk]);
          acc[0][bi] = __builtin_amdgcn_fdot2(w2[0][kk], x, acc[0][bi], false);
          acc[1][bi] = __builtin_amdgcn_fdot2(w2[1][kk], x, acc[1][bi], false);
          acc[2][bi] = __builtin_amdgcn_fdot2(w2[2][kk], x, acc[2][bi], false);
          acc[3][bi] = __builtin_amdgcn_fdot2(w2[3][kk], x, acc[3][bi], false);
        }
#pragma unroll
        for (int kk = 0; kk < KHALF / 2; ++kk) {
          v2h x = __builtin_bit_cast(v2h, ph[kk]);
          acc[0][bi] = __builtin_amdgcn_fdot2(w2[0][8 + kk], x, acc[0][bi], false);
          acc[1][bi] = __builtin_amdgcn_fdot2(w2[1][8 + kk], x, acc[1][bi], false);
          acc[2][bi] = __builtin_amdgcn_fdot2(w2[2][8 + kk], x, acc[2][bi], false);
          acc[3][bi] = __builtin_amdgcn_fdot2(w2[3][8 + kk], x, acc[3][bi], false);
        }
      }
    }
#pragma unroll
    for (int jj = 0; jj < 4; ++jj) {
      int r = jg * 4 + jj;
#pragma unroll
      for (int bi = 0; bi < BPB; ++bi)
        p_s[ks][r * BPB + bi] = acc[jj][bi];
    }
    __syncthreads();   // B: p_s complete; in2 x-half dead

    // ---- prefetch x(t+1) into in2 x-half (cached; off critical path) ----
    if (more) {
      int e = ev[(t + 1) * NB + b0 + sb2];
      float4 v0 = *(const float4*)(path + (size_t)e * NH + off4);
      int p0 = (tid & 127) * 2;
      unsigned int* d = &in2[sb2][fpadp(p0)];
      d[0] = __builtin_bit_cast(unsigned int, __builtin_amdgcn_cvt_pkrtz(v0.x, v0.y));
      d[1] = __builtin_bit_cast(unsigned int, __builtin_amdgcn_cvt_pkrtz(v0.z, v0.w));
    }

    // ---- reduce 32 k-slices + bias ----
    if (tid < NJ * BPB) {
      float s = 0.f;
#pragma unroll
      for (int k2 = 0; k2 < 32; ++k2) s += p_s[k2][tid];
      int r = tid >> 2;
      s += gate_b[(r >> 4) * NH + u0 + (r & 15)];
      zred[tid] = s;
    }
    __syncthreads();   // C: zred complete

    // ---- gates + state update + handoff (wave 0 only) ----
    if (tid < BPB * UPB) {
      int bi = tid >> 4, uu = tid & 15;
      float zi = zred[(uu) * BPB + bi];
      float zf = zred[(UPB + uu) * BPB + bi];
      float zg = zred[(2 * UPB + uu) * BPB + bi];
      float zo = zred[(3 * UPB + uu) * BPB + bi];
      float ig = 1.f / (1.f + expf(-zi));
      float fg = 1.f / (1.f + expf(-zf));
      float gg = tanhf(zg);
      float ogv = 1.f / (1.f + expf(-zo));
      float cv = fmaf(fg, c_s[bi][uu], ig * gg);
      float hvv = ogv * tanhf(cv);
      c_s[bi][uu] = cv;
      int b = b0 + bi, u = u0 + uu;
      if (more) {
        float* hdst = hbuf + ((size_t)((t + 1) & 1) * NB + b) * NH + u;
        __hip_atomic_store(hdst, hvv, __ATOMIC_RELAXED, __HIP_MEMORY_SCOPE_SYSTEM);
      }
      // announce: wave-level drain of the h stores, then per-producer word
      if (more && tid == 0) {
        asm volatile("s_waitcnt vmcnt(0)" ::: "memory");
        int nv = t + 1;
        asm volatile("global_store_dword %0, %1, off sc0 sc1"
                     :: "v"(myprog), "v"(nv) : "memory");
      }
      // output stores off the critical path (after the signal)
      size_t o0 = ((size_t)t * NB + b) * NH + u;
      out[o0] = hvv;
      out[plane + o0] = cv;
      out[2 * plane + o0] = ogv;
    }
    // no end-of-step barrier: next iteration's poll + A0 covers it
  }
}

extern "C" void kernel_launch(void* const* d_in, const int* in_sizes, int n_in,
                              void* d_out, int out_size, void* d_ws, size_t ws_size,
                              hipStream_t stream) {
  const int* ev = (const int*)d_in[0];
  const int* parents = (const int*)d_in[1];
  const float* weight = (const float*)d_in[2];
  const float* emb = (const float*)d_in[3];
  const float* gate_w = (const float*)d_in[4];
  const float* gate_b = (const float*)d_in[5];
  float* out = (float*)d_out;

  char* ws = (char*)d_ws;
  float* path = (float*)ws;
  size_t path_bytes = (size_t)NV * NH * sizeof(float);
  float* hbuf = (float*)(ws + path_bytes);
  int* prog = (int*)(ws + path_bytes + (size_t)2 * NB * NH * sizeof(float));

  init_kernel<<<(2 * NB * NH + 255) / 256, 256, 0, stream>>>(hbuf, prog);
  path_kernel<<<NV, 256, 0, stream>>>(parents, weight, emb, path);
  lstm_kernel<<<NGRP * BPG, NTH, 0, stream>>>(ev, path, gate_w, gate_b, hbuf, prog, out);
}